// Round 10
// baseline (268.417 us; speedup 1.0000x reference)
//
#include <hip/hip_runtime.h>
#include <math.h>

// (B,L,DM,H,DH) = (4,2048,768,12,64)
constexpr int B  = 4;
constexpr int L  = 2048;
constexpr int DM = 768;
constexpr int H  = 12;
constexpr int DH = 64;
constexpr int M  = B * L;          // 8192
constexpr float LOG2E = 1.4426950408889634f;

typedef __attribute__((ext_vector_type(8)))  _Float16       f16x8;
typedef __attribute__((ext_vector_type(8)))  short          s16x8;
typedef __attribute__((ext_vector_type(4)))  unsigned short u16x4;
typedef __attribute__((ext_vector_type(8)))  unsigned short u16x8;
typedef __attribute__((ext_vector_type(4)))  unsigned int   u32x4;
typedef __attribute__((ext_vector_type(16))) float          f32x16;
typedef __attribute__((ext_vector_type(4)))  float          f32x4;
typedef unsigned short ushort_t;
typedef unsigned int   uint_t;

#define MFMA16(a, b, c) __builtin_amdgcn_mfma_f32_32x32x16_f16((a), (b), (c), 0, 0, 0)

#if __has_builtin(__builtin_amdgcn_exp2f)
#define EXP2(x) __builtin_amdgcn_exp2f(x)
#else
#define EXP2(x) exp2f(x)
#endif

__device__ __forceinline__ ushort_t h_bits(_Float16 h) {
    return __builtin_bit_cast(ushort_t, h);
}
__device__ __forceinline__ uint_t pkrtz(float a, float b) {
    return __builtin_bit_cast(uint_t, __builtin_amdgcn_cvt_pkrtz(a, b));
}
__device__ __forceinline__ void plswap(uint_t& x, uint_t& y) {
    // v_permlane32_swap_b32 vdst, vsrc: vdst[32:63] <-> vsrc[0:31].
    // After plswap(x,y): x = {x_lo, y_lo}, y = {x_hi, y_hi}.
    asm volatile("v_permlane32_swap_b32 %0, %1" : "+v"(x), "+v"(y));
}
// max/sum with the xor-32 partner lane via permlane (VALU, no LDS pipe).
// CRITICAL: the duplicate must be made through an early-clobber asm mov --
// with a plain copy (b = a) both plswap operands hold the same SSA value and
// the register allocator may coalesce them into ONE register, emitting
// v_permlane32_swap_b32 v5, v5 (in-place half swap -> wrong reduction).
__device__ __forceinline__ float half_max(float v) {
    uint_t a = __builtin_bit_cast(uint_t, v);
    uint_t b;
    asm("v_mov_b32 %0, %1" : "=&v"(b) : "v"(a));   // distinct reg, opaque copy
    plswap(a, b);
    return fmaxf(__builtin_bit_cast(float, a), __builtin_bit_cast(float, b));
}
__device__ __forceinline__ float half_sum(float v) {
    uint_t a = __builtin_bit_cast(uint_t, v);
    uint_t b;
    asm("v_mov_b32 %0, %1" : "=&v"(b) : "v"(a));
    plswap(a, b);
    return __builtin_bit_cast(float, a) + __builtin_bit_cast(float, b);
}

// ---------------------------------------------------------------------------
// Prep: cast x (fp32) -> f16
// ---------------------------------------------------------------------------
__global__ __launch_bounds__(256) void cast_x(
    const float* __restrict__ x, ushort_t* __restrict__ xh, int n)
{
    const int i = (blockIdx.x * 256 + threadIdx.x) * 4;
    if (i >= n) return;
    const float4 v = *reinterpret_cast<const float4*>(&x[i]);
    u16x4 hh;
    hh[0] = h_bits((_Float16)v.x); hh[1] = h_bits((_Float16)v.y);
    hh[2] = h_bits((_Float16)v.z); hh[3] = h_bits((_Float16)v.w);
    *reinterpret_cast<u16x4*>(&xh[i]) = hh;
}

// ---------------------------------------------------------------------------
// Prep: all 4 weights [768x768] fp32 -> transposed f16 WT[n][k], one launch.
// ---------------------------------------------------------------------------
__global__ __launch_bounds__(256) void wtransAll(
    const float* __restrict__ W0, const float* __restrict__ W1,
    const float* __restrict__ W2, const float* __restrict__ W3,
    ushort_t* __restrict__ T0, ushort_t* __restrict__ T1,
    ushort_t* __restrict__ T2, ushort_t* __restrict__ T3)
{
    __shared__ ushort_t Tls[64][72];
    const int t = threadIdx.x;
    const int k0 = blockIdx.x * 64, n0 = blockIdx.y * 64, wsel = blockIdx.z;
    const float* W = wsel == 0 ? W0 : wsel == 1 ? W1 : wsel == 2 ? W2 : W3;
    ushort_t*    T = wsel == 0 ? T0 : wsel == 1 ? T1 : wsel == 2 ? T2 : T3;

    #pragma unroll
    for (int it = 0; it < 4; ++it) {
        const int idx = it * 256 + t;
        const int r = idx >> 4, c = (idx & 15) * 4;
        const float4 v = *reinterpret_cast<const float4*>(
            &W[(size_t)(k0 + r) * 768 + n0 + c]);
        Tls[c + 0][r] = h_bits((_Float16)v.x);
        Tls[c + 1][r] = h_bits((_Float16)v.y);
        Tls[c + 2][r] = h_bits((_Float16)v.z);
        Tls[c + 3][r] = h_bits((_Float16)v.w);
    }
    __syncthreads();
    #pragma unroll
    for (int it = 0; it < 4; ++it) {
        const int idx = it * 256 + t;
        const int r = idx >> 4, c = (idx & 15) * 4;
        *reinterpret_cast<u16x4*>(&T[(size_t)(n0 + r) * 768 + k0 + c]) =
            *reinterpret_cast<const u16x4*>(&Tls[r][c]);
    }
}

// ---------------------------------------------------------------------------
// Fused QKV projection GEMM. Grid (64, 24): blockIdx.y>>3 = {Q,K,V}.
// Tile 128x96, 4 waves, BK=32, reg-prefetch. Shared-pool LDS (17.9KB).
// Q: f16 * LOG2E.  K: f16.  V: f16 transposed via 3x32-row LDS bounce.
// ---------------------------------------------------------------------------
__global__ __launch_bounds__(256) void qkvproj(
    const ushort_t* __restrict__ xh,
    const ushort_t* __restrict__ WqT, const ushort_t* __restrict__ WkT,
    const ushort_t* __restrict__ WvT,
    const float* __restrict__ bq, const float* __restrict__ bk,
    const float* __restrict__ bv,
    ushort_t* __restrict__ qhb, ushort_t* __restrict__ khb,
    ushort_t* __restrict__ vtb)
{
    constexpr int KD = 768;
    __shared__ __align__(16) char pool[17920];
    ushort_t (*Ahs)[40] = (ushort_t(*)[40])pool;            // 128x40 = 10240B
    ushort_t (*Whs)[40] = (ushort_t(*)[40])(pool + 10240);  //  96x40 =  7680B
    ushort_t (*Ots)[136] = (ushort_t(*)[136])pool;          //  32x136 = 8704B

    const int t = threadIdx.x, lane = t & 63, w = t >> 6;
    const int l31 = lane & 31, l5 = lane >> 5;
    const int which = blockIdx.y >> 3;
    const int m0 = blockIdx.x * 128, n0 = (blockIdx.y & 7) * 96;
    const ushort_t* Wh = which == 0 ? WqT : which == 1 ? WkT : WvT;
    const float* bias  = which == 0 ? bq  : which == 1 ? bk  : bv;
    const int arow = t >> 1, acol = (t & 1) * 16;
    const int wrow = t >> 1, wcol = (t & 1) * 16;

    f32x16 acc[3] = {};
    s16x8 rA0, rA1, rW0, rW1;

    auto LOAD = [&](int k0) {
        const size_t ab = (size_t)(m0 + arow) * KD + k0 + acol;
        rA0 = *reinterpret_cast<const s16x8*>(&xh[ab]);
        rA1 = *reinterpret_cast<const s16x8*>(&xh[ab + 8]);
        if (t < 192) {
            const size_t wb = (size_t)(n0 + wrow) * KD + k0 + wcol;
            rW0 = *reinterpret_cast<const s16x8*>(&Wh[wb]);
            rW1 = *reinterpret_cast<const s16x8*>(&Wh[wb + 8]);
        }
    };
    auto STORE = [&]() {
        *reinterpret_cast<s16x8*>(&Ahs[arow][acol])     = rA0;
        *reinterpret_cast<s16x8*>(&Ahs[arow][acol + 8]) = rA1;
        if (t < 192) {
            *reinterpret_cast<s16x8*>(&Whs[wrow][wcol])     = rW0;
            *reinterpret_cast<s16x8*>(&Whs[wrow][wcol + 8]) = rW1;
        }
    };

    LOAD(0); STORE();
    __syncthreads();

    for (int k0 = 0; k0 < KD; k0 += 32) {
        if (k0 + 32 < KD) LOAD(k0 + 32);
        #pragma unroll
        for (int ks = 0; ks < 2; ++ks) {
            const int koff = ks * 16 + l5 * 8;
            const f16x8 af = *reinterpret_cast<const f16x8*>(&Ahs[w * 32 + l31][koff]);
            #pragma unroll
            for (int nt = 0; nt < 3; ++nt) {
                const f16x8 wf = *reinterpret_cast<const f16x8*>(&Whs[nt * 32 + l31][koff]);
                acc[nt] = MFMA16(af, wf, acc[nt]);
            }
        }
        __syncthreads();
        if (k0 + 32 < KD) STORE();
        __syncthreads();
    }

    if (which == 2) {
        // V: 3 chunks of 32 n-rows; LDS bounce -> coalesced vt[b][h][dh][l].
        const int bq_ = m0 >> 11, lq = m0 & 2047;
        #pragma unroll
        for (int nt = 0; nt < 3; ++nt) {
            const float bb = bias[n0 + nt * 32 + l31];
            __syncthreads();
            #pragma unroll
            for (int reg = 0; reg < 16; ++reg) {
                const int rowl = (reg & 3) + 8 * (reg >> 2) + 4 * l5;
                Ots[l31][w * 32 + rowl] = h_bits((_Float16)(acc[nt][reg] + bb));
            }
            __syncthreads();
            #pragma unroll
            for (int it = 0; it < 2; ++it) {    // 32 rows x 16 chunks / 256
                const int idx = it * 256 + t;
                const int r = idx >> 4, c = (idx & 15) * 8;
                const int n = n0 + nt * 32 + r, hh = n >> 6, dh = n & 63;
                *reinterpret_cast<u16x8*>(
                    &vtb[((((size_t)bq_ * H + hh) * DH + dh) << 11) + lq + c]) =
                    *reinterpret_cast<const u16x8*>(&Ots[r][c]);
            }
        }
    } else {
        ushort_t* out = which == 0 ? qhb : khb;
        const float qs = which == 0 ? LOG2E : 1.0f;
        #pragma unroll
        for (int nt = 0; nt < 3; ++nt) {
            const int n = n0 + nt * 32 + l31;
            const float bb = bias[n];
            #pragma unroll
            for (int reg = 0; reg < 16; ++reg) {
                const int rowl = (reg & 3) + 8 * (reg >> 2) + 4 * l5;
                const int m = m0 + w * 32 + rowl;
                out[(size_t)m * 768 + n] = h_bits((_Float16)((acc[nt][reg] + bb) * qs));
            }
        }
    }
}

// ---------------------------------------------------------------------------
// Output projection GEMM: out[M,768] fp32 = pf[M,768] f16 x WdT + bd.
// ---------------------------------------------------------------------------
__global__ __launch_bounds__(256) void gemm_out(
    const ushort_t* __restrict__ Ah, const ushort_t* __restrict__ Wh,
    const float* __restrict__ bias, float* __restrict__ out)
{
    constexpr int KD = 768;
    __shared__ __align__(16) ushort_t Ahs[128][40];
    __shared__ __align__(16) ushort_t Whs[96][40];

    const int t = threadIdx.x, lane = t & 63, w = t >> 6;
    const int l31 = lane & 31, l5 = lane >> 5;
    const int m0 = blockIdx.x * 128, n0 = blockIdx.y * 96;
    const int arow = t >> 1, acol = (t & 1) * 16;
    const int wrow = t >> 1, wcol = (t & 1) * 16;

    f32x16 acc[3] = {};
    s16x8 rA0, rA1, rW0, rW1;

    auto LOAD = [&](int k0) {
        const size_t ab = (size_t)(m0 + arow) * KD + k0 + acol;
        rA0 = *reinterpret_cast<const s16x8*>(&Ah[ab]);
        rA1 = *reinterpret_cast<const s16x8*>(&Ah[ab + 8]);
        if (t < 192) {
            const size_t wb = (size_t)(n0 + wrow) * KD + k0 + wcol;
            rW0 = *reinterpret_cast<const s16x8*>(&Wh[wb]);
            rW1 = *reinterpret_cast<const s16x8*>(&Wh[wb + 8]);
        }
    };
    auto STORE = [&]() {
        *reinterpret_cast<s16x8*>(&Ahs[arow][acol])     = rA0;
        *reinterpret_cast<s16x8*>(&Ahs[arow][acol + 8]) = rA1;
        if (t < 192) {
            *reinterpret_cast<s16x8*>(&Whs[wrow][wcol])     = rW0;
            *reinterpret_cast<s16x8*>(&Whs[wrow][wcol + 8]) = rW1;
        }
    };

    LOAD(0); STORE();
    __syncthreads();

    for (int k0 = 0; k0 < KD; k0 += 32) {
        if (k0 + 32 < KD) LOAD(k0 + 32);
        #pragma unroll
        for (int ks = 0; ks < 2; ++ks) {
            const int koff = ks * 16 + l5 * 8;
            const f16x8 af = *reinterpret_cast<const f16x8*>(&Ahs[w * 32 + l31][koff]);
            #pragma unroll
            for (int nt = 0; nt < 3; ++nt) {
                const f16x8 wf = *reinterpret_cast<const f16x8*>(&Whs[nt * 32 + l31][koff]);
                acc[nt] = MFMA16(af, wf, acc[nt]);
            }
        }
        __syncthreads();
        if (k0 + 32 < KD) STORE();
        __syncthreads();
    }

    #pragma unroll
    for (int nt = 0; nt < 3; ++nt) {
        const int n = n0 + nt * 32 + l31;
        const float bb = bias[n];
        #pragma unroll
        for (int reg = 0; reg < 16; ++reg) {
            const int rowl = (reg & 3) + 8 * (reg >> 2) + 4 * l5;
            const int m = m0 + w * 32 + rowl;
            out[(size_t)m * 768 + n] = acc[nt][reg] + bb;
        }
    }
}

// ---------------------------------------------------------------------------
// Flash attention, f16 MFMA 32x32x16, swapped QK^T, 1-term.
// Grid (L/64, H, B) = 1536 blocks; 128 threads = 2 waves; wave owns 32 q rows.
// Tree reductions + permlane half-exchange (no ds_bpermute on critical path).
// ---------------------------------------------------------------------------
__global__ __launch_bounds__(128) void attn2(
    const ushort_t* __restrict__ qh, const ushort_t* __restrict__ kh,
    const ushort_t* __restrict__ vt, ushort_t* __restrict__ pf)
{
    __shared__ __align__(16) ushort_t Khs[64][72];
    __shared__ __align__(16) ushort_t Vts[64][72];
    __shared__ __align__(16) float scale_s[2][32];
    __shared__ __align__(16) float l_s[2][32];

    const int t = threadIdx.x, lane = t & 63, w = t >> 6;  // w in {0,1}
    const int l31 = lane & 31, l5 = lane >> 5;
    const int qt = blockIdx.x, h = blockIdx.y, b = blockIdx.z;

    // Q fragments (B-operand: col=q=l31, k=d)
    const int qrow = qt * 64 + w * 32 + l31;
    const size_t qb = ((size_t)(b * L + qrow)) * 768 + h * 64;
    f16x8 qfh[4];
    #pragma unroll
    for (int ks = 0; ks < 4; ++ks)
        qfh[ks] = *reinterpret_cast<const f16x8*>(&qh[qb + ks * 16 + l5 * 8]);

    f32x16 o[2] = {};
    float m_run = -3.0e38f, l_run = 0.0f;
    const int sr = t >> 3, scc = (t & 7) * 8;   // sr in 0..15
    s16x8 rK0, rK1, rK2, rK3, rV0, rV1, rV2, rV3;

    auto LOADT = [&](int kt) {
        const size_t kg = ((size_t)(b * L + kt * 64 + sr)) * 768 + h * 64 + scc;
        rK0 = *reinterpret_cast<const s16x8*>(&kh[kg]);
        rK1 = *reinterpret_cast<const s16x8*>(&kh[kg + (size_t)16 * 768]);
        rK2 = *reinterpret_cast<const s16x8*>(&kh[kg + (size_t)32 * 768]);
        rK3 = *reinterpret_cast<const s16x8*>(&kh[kg + (size_t)48 * 768]);
        const size_t vg = (((size_t)b * H + h) * DH + sr) * (size_t)L + kt * 64 + scc;
        rV0 = *reinterpret_cast<const s16x8*>(&vt[vg]);
        rV1 = *reinterpret_cast<const s16x8*>(&vt[vg + (size_t)16 * L]);
        rV2 = *reinterpret_cast<const s16x8*>(&vt[vg + (size_t)32 * L]);
        rV3 = *reinterpret_cast<const s16x8*>(&vt[vg + (size_t)48 * L]);
    };
    auto STORET = [&]() {
        *reinterpret_cast<s16x8*>(&Khs[sr][scc])      = rK0;
        *reinterpret_cast<s16x8*>(&Khs[sr + 16][scc]) = rK1;
        *reinterpret_cast<s16x8*>(&Khs[sr + 32][scc]) = rK2;
        *reinterpret_cast<s16x8*>(&Khs[sr + 48][scc]) = rK3;
        *reinterpret_cast<s16x8*>(&Vts[sr][scc])      = rV0;
        *reinterpret_cast<s16x8*>(&Vts[sr + 16][scc]) = rV1;
        *reinterpret_cast<s16x8*>(&Vts[sr + 32][scc]) = rV2;
        *reinterpret_cast<s16x8*>(&Vts[sr + 48][scc]) = rV3;
    };

    LOADT(0); STORET();
    __syncthreads();

    for (int kt = 0; kt < L / 64; ++kt) {
        if (kt + 1 < L / 64) LOADT(kt + 1);

        // S^T = K * Q^T (1-term f16)
        f32x16 st[2] = {};
        #pragma unroll
        for (int mt = 0; mt < 2; ++mt) {
            #pragma unroll
            for (int ks = 0; ks < 4; ++ks) {
                const f16x8 kf = *reinterpret_cast<const f16x8*>(
                    &Khs[mt * 32 + l31][ks * 16 + l5 * 8]);
                st[mt] = MFMA16(kf, qfh[ks], st[mt]);
            }
        }

        // row max: depth-5 tree over 32 regs, then permlane half-exchange
        float mx[8];
        #pragma unroll
        for (int i = 0; i < 8; ++i)
            mx[i] = fmaxf(fmaxf(st[0][i], st[0][i + 8]),
                          fmaxf(st[1][i], st[1][i + 8]));
        mx[0] = fmaxf(mx[0], mx[4]); mx[1] = fmaxf(mx[1], mx[5]);
        mx[2] = fmaxf(mx[2], mx[6]); mx[3] = fmaxf(mx[3], mx[7]);
        mx[0] = fmaxf(fmaxf(mx[0], mx[2]), fmaxf(mx[1], mx[3]));
        const float pmax = half_max(mx[0]);

        if (!__all(pmax - m_run <= 12.0f)) {      // defer-max: rescale rarely
            const float mnew = fmaxf(m_run, pmax);
            const float sc = EXP2(m_run - mnew);
            m_run = mnew;
            l_run *= sc;
            scale_s[w][l31] = sc;
            #pragma unroll
            for (int rg = 0; rg < 4; ++rg) {
                const f32x4 sc4 =
                    *reinterpret_cast<const f32x4*>(&scale_s[w][8 * rg + 4 * l5]);
                #pragma unroll
                for (int j = 0; j < 4; ++j) {
                    o[0][rg * 4 + j] *= sc4[j];
                    o[1][rg * 4 + j] *= sc4[j];
                }
            }
        }

        // exp2 + 4-partial sum tree
        float s0 = 0.f, s1 = 0.f, s2 = 0.f, s3 = 0.f;
        #pragma unroll
        for (int mt = 0; mt < 2; ++mt)
            #pragma unroll
            for (int e = 0; e < 16; e += 4) {
                const float p0 = EXP2(st[mt][e + 0] - m_run);
                const float p1 = EXP2(st[mt][e + 1] - m_run);
                const float p2 = EXP2(st[mt][e + 2] - m_run);
                const float p3 = EXP2(st[mt][e + 3] - m_run);
                st[mt][e + 0] = p0; st[mt][e + 1] = p1;
                st[mt][e + 2] = p2; st[mt][e + 3] = p3;
                s0 += p0; s1 += p1; s2 += p2; s3 += p3;
            }
        l_run += half_sum((s0 + s1) + (s2 + s3));

        // pack P -> PV A-operand fragments (cvt_pkrtz + permlane32_swap)
        f16x8 pa[4];
        #pragma unroll
        for (int mt = 0; mt < 2; ++mt) {
            #pragma unroll
            for (int hf = 0; hf < 2; ++hf) {
                uint_t a0 = pkrtz(st[mt][8 * hf + 0], st[mt][8 * hf + 1]);
                uint_t a1 = pkrtz(st[mt][8 * hf + 2], st[mt][8 * hf + 3]);
                uint_t b0 = pkrtz(st[mt][8 * hf + 4], st[mt][8 * hf + 5]);
                uint_t b1 = pkrtz(st[mt][8 * hf + 6], st[mt][8 * hf + 7]);
                plswap(a0, b0);
                plswap(a1, b1);
                u32x4 pk4; pk4[0] = a0; pk4[1] = a1; pk4[2] = b0; pk4[3] = b1;
                pa[mt * 2 + hf] = __builtin_bit_cast(f16x8, pk4);
            }
        }

        // O += P * V
        #pragma unroll
        for (int ks = 0; ks < 4; ++ks) {
            const int koff = ks * 16 + l5 * 8;
            #pragma unroll
            for (int dt = 0; dt < 2; ++dt) {
                const f16x8 vb =
                    *reinterpret_cast<const f16x8*>(&Vts[dt * 32 + l31][koff]);
                o[dt] = MFMA16(pa[ks], vb, o[dt]);
            }
        }

        __syncthreads();
        if (kt + 1 < L / 64) STORET();
        __syncthreads();
    }

    l_s[w][l31] = l_run;
    const size_t ob = ((size_t)(b * L + qt * 64 + w * 32)) * 768 + h * 64;
    #pragma unroll
    for (int rg = 0; rg < 4; ++rg) {
        const f32x4 lv = *reinterpret_cast<const f32x4*>(&l_s[w][8 * rg + 4 * l5]);
        #pragma unroll
        for (int j = 0; j < 4; ++j) {
            const float inv = 1.0f / lv[j];
            const int rowl = j + 8 * rg + 4 * l5;
            #pragma unroll
            for (int dt = 0; dt < 2; ++dt) {
                pf[ob + (size_t)rowl * 768 + dt * 32 + l31] =
                    h_bits((_Float16)(o[dt][rg * 4 + j] * inv));
            }
        }
    }
}

// ---------------------------------------------------------------------------
extern "C" void kernel_launch(void* const* d_in, const int* in_sizes, int n_in,
                              void* d_out, int out_size, void* d_ws, size_t ws_size,
                              hipStream_t stream)
{
    const float* x  = (const float*)d_in[0];
    const float* Wq = (const float*)d_in[1];
    const float* bq = (const float*)d_in[2];
    const float* Wk = (const float*)d_in[3];
    const float* bk = (const float*)d_in[4];
    const float* Wv = (const float*)d_in[5];
    const float* bv = (const float*)d_in[6];
    const float* Wd = (const float*)d_in[7];
    const float* bd = (const float*)d_in[8];
    float* out = (float*)d_out;

    constexpr size_t S  = (size_t)M * 768;
    constexpr size_t WS = (size_t)768 * 768;
    ushort_t* p = (ushort_t*)d_ws;
    ushort_t* xh  = p; p += S;
    ushort_t* qhb = p; p += S;
    ushort_t* khb = p; p += S;
    ushort_t* vtb = p; p += S;
    ushort_t* WqT = p; p += WS;
    ushort_t* WkT = p; p += WS;
    ushort_t* WvT = p; p += WS;
    ushort_t* WdT = p; p += WS;
    ushort_t* pfb = xh;                      // xh dead after QKV projection

    cast_x<<<dim3((int)(S / 1024)), dim3(256), 0, stream>>>(x, xh, (int)S);
    wtransAll<<<dim3(12, 12, 4), dim3(256), 0, stream>>>(
        Wq, Wk, Wv, Wd, WqT, WkT, WvT, WdT);

    // fused Q/K/V projections: grid (64, 24)
    qkvproj<<<dim3(M / 128, 24), dim3(256), 0, stream>>>(
        xh, WqT, WkT, WvT, bq, bk, bv, qhb, khb, vtb);

    // attention: 2-wave blocks
    attn2<<<dim3(L / 64, H, B), dim3(128), 0, stream>>>(qhb, khb, vtb, pfb);

    // output projection
    gemm_out<<<dim3(M / 128, DM / 96), dim3(256), 0, stream>>>(pfb, WdT, bd, out);
}